// Round 1
// baseline (731.247 us; speedup 1.0000x reference)
//
#include <hip/hip_runtime.h>
#include <hip/hip_bf16.h>

typedef __attribute__((ext_vector_type(8))) short short8;
typedef __attribute__((ext_vector_type(8))) unsigned short ushort8;
typedef __attribute__((ext_vector_type(4))) unsigned short ushort4v;
typedef __attribute__((ext_vector_type(4))) float f32x4;
typedef __attribute__((ext_vector_type(4))) unsigned int uint4v;

#define MFMA16(a,b,c) __builtin_amdgcn_mfma_f32_16x16x32_bf16((a),(b),(c),0,0,0)

__device__ __forceinline__ unsigned short f2bf(float f){
    union { float f; unsigned int u; } c; c.f = f;
    unsigned int u = c.u;
    u = (u + 0x7fffu + ((u >> 16) & 1u)) >> 16;
    return (unsigned short)u;
}
__device__ __forceinline__ float bf2f(unsigned short s){
    union { unsigned int u; float f; } c; c.u = ((unsigned int)s) << 16;
    return c.f;
}
__device__ __forceinline__ void split2(float f, unsigned short &h, unsigned short &l){
    h = f2bf(f);
    l = f2bf(f - bf2f(h));
}

// ---------------- weight pre-split (fp32 -> bf16 hi/lo planes) ----------------
__global__ void split_kernel(const float* __restrict__ in, unsigned short* __restrict__ h,
                             unsigned short* __restrict__ l, int n){
    int i = blockIdx.x * 256 + threadIdx.x;
    if (i < n){
        unsigned short hh, ll;
        split2(in[i], hh, ll);
        h[i] = hh; l[i] = ll;
    }
}

// ---------------- split-bf16 GEMM: C = A @ W^T + bias ----------------
// A: (M,K). AMODE 0: fp32, split on the fly. AMODE 1: packed uint (hi|lo<<16).
// W planes: (N,K) bf16 hi/lo. Tile 128x128, BK=32, 4 waves (each 64x64 = 4x4 frags).
// EMODE 0: C fp32 (M,N) + bias. EMODE 1: write q/k/v packed uint (B,12,512,64) + bias.
template<int AMODE, int EMODE>
__global__ __launch_bounds__(256, 2)
void gemm_split(const void* __restrict__ Avoid,
                const unsigned short* __restrict__ Wh, const unsigned short* __restrict__ Wl,
                const float* __restrict__ bias, int N, int K,
                float* __restrict__ C,
                unsigned int* __restrict__ qo, unsigned int* __restrict__ ko,
                unsigned int* __restrict__ vo)
{
    extern __shared__ unsigned short lds[];
    constexpr int LDT = 40;          // padded row (32 + 8) -> bank-conflict-free-ish
    constexpr int TSZ = 128 * LDT;   // one buffer
    unsigned short* Ah = lds;
    unsigned short* Al = lds + 2 * TSZ;
    unsigned short* Bh = lds + 4 * TSZ;
    unsigned short* Bl = lds + 6 * TSZ;

    const int t = threadIdx.x;
    const int l = t & 63, w = t >> 6;
    const int wr = (w >> 1) * 64, wc = (w & 1) * 64;
    const int m0 = blockIdx.x * 128, j0 = blockIdx.y * 128;
    const int NT = K >> 5;

    const int a_r = t >> 3, a_c = (t & 7) * 4;   // A staging: 4 rows (stride 32), 4 floats
    const int b_r = t >> 2, b_c = (t & 3) * 8;   // B staging: 2 rows (stride 64), 8 ushorts

    f32x4  raf[4];
    uint4v rau[4];
    ushort8 rbh[2], rbl[2];
    f32x4 acc[4][4] = {};

    auto gload = [&](int kt){
        if constexpr (AMODE == 0){
            const float* A = (const float*)Avoid;
            #pragma unroll
            for (int i = 0; i < 4; ++i)
                raf[i] = *(const f32x4*)(A + (size_t)(m0 + i*32 + a_r)*K + kt*32 + a_c);
        } else {
            const unsigned int* A = (const unsigned int*)Avoid;
            #pragma unroll
            for (int i = 0; i < 4; ++i)
                rau[i] = *(const uint4v*)(A + (size_t)(m0 + i*32 + a_r)*K + kt*32 + a_c);
        }
        #pragma unroll
        for (int i = 0; i < 2; ++i){
            int row = i*64 + b_r;
            rbh[i] = *(const ushort8*)(Wh + (size_t)(j0 + row)*K + kt*32 + b_c);
            rbl[i] = *(const ushort8*)(Wl + (size_t)(j0 + row)*K + kt*32 + b_c);
        }
    };
    auto lstore = [&](int buf){
        #pragma unroll
        for (int i = 0; i < 4; ++i){
            int base = buf*TSZ + (i*32 + a_r)*LDT + a_c;
            unsigned short h0,h1,h2,h3,l0,l1,l2,l3;
            if constexpr (AMODE == 0){
                split2(raf[i][0], h0, l0); split2(raf[i][1], h1, l1);
                split2(raf[i][2], h2, l2); split2(raf[i][3], h3, l3);
            } else {
                h0 = (unsigned short)(rau[i][0] & 0xffffu); l0 = (unsigned short)(rau[i][0] >> 16);
                h1 = (unsigned short)(rau[i][1] & 0xffffu); l1 = (unsigned short)(rau[i][1] >> 16);
                h2 = (unsigned short)(rau[i][2] & 0xffffu); l2 = (unsigned short)(rau[i][2] >> 16);
                h3 = (unsigned short)(rau[i][3] & 0xffffu); l3 = (unsigned short)(rau[i][3] >> 16);
            }
            ushort4v hv = {h0,h1,h2,h3}, lv = {l0,l1,l2,l3};
            *(ushort4v*)(Ah + base) = hv;
            *(ushort4v*)(Al + base) = lv;
        }
        #pragma unroll
        for (int i = 0; i < 2; ++i){
            int base = buf*TSZ + (i*64 + b_r)*LDT + b_c;
            *(ushort8*)(Bh + base) = rbh[i];
            *(ushort8*)(Bl + base) = rbl[i];
        }
    };

    gload(0);
    lstore(0);
    __syncthreads();
    int cur = 0;

    for (int kt = 0; kt < NT; ++kt){
        if (kt + 1 < NT) gload(kt + 1);

        const int ko_ = (l >> 4) * 8;
        short8 afh[4], afl[4], bfh[4], bfl[4];
        #pragma unroll
        for (int f = 0; f < 4; ++f){
            int arow = wr + f*16 + (l & 15);
            int brow = wc + f*16 + (l & 15);
            afh[f] = *(const short8*)(Ah + cur*TSZ + arow*LDT + ko_);
            afl[f] = *(const short8*)(Al + cur*TSZ + arow*LDT + ko_);
            bfh[f] = *(const short8*)(Bh + cur*TSZ + brow*LDT + ko_);
            bfl[f] = *(const short8*)(Bl + cur*TSZ + brow*LDT + ko_);
        }
        #pragma unroll
        for (int fr = 0; fr < 4; ++fr)
            #pragma unroll
            for (int fc = 0; fc < 4; ++fc){
                acc[fr][fc] = MFMA16(afh[fr], bfh[fc], acc[fr][fc]);
                acc[fr][fc] = MFMA16(afh[fr], bfl[fc], acc[fr][fc]);
                acc[fr][fc] = MFMA16(afl[fr], bfh[fc], acc[fr][fc]);
            }

        if (kt + 1 < NT) lstore(cur ^ 1);
        __syncthreads();
        cur ^= 1;
    }

    // epilogue: D layout col = lane&15, row = (lane>>4)*4 + reg
    #pragma unroll
    for (int fr = 0; fr < 4; ++fr){
        #pragma unroll
        for (int fc = 0; fc < 4; ++fc){
            #pragma unroll
            for (int r = 0; r < 4; ++r){
                int m = m0 + wr + fr*16 + ((l >> 4) << 2) + r;
                int j = j0 + wc + fc*16 + (l & 15);
                float val = acc[fr][fc][r] + bias[j];
                if constexpr (EMODE == 0){
                    C[(size_t)m * N + j] = val;
                } else {
                    int sec = j / 768;
                    int off = j - sec * 768;
                    int head = off >> 6, d = off & 63;
                    int bb = m >> 9, n = m & 511;
                    unsigned short hh, ll; split2(val, hh, ll);
                    unsigned int packed = (unsigned int)hh | ((unsigned int)ll << 16);
                    unsigned int* dst = (sec == 0) ? qo : (sec == 1) ? ko : vo;
                    dst[(((size_t)bb * 12 + head) * 512 + n) * 64 + d] = packed;
                }
            }
        }
    }
}

// ---------------- fused flash attention (split-bf16 MFMA) ----------------
// grid (384 = b*12+h, 8 = q-tile of 64). block 256 = 4 waves; wave w owns 16 q-rows.
__global__ __launch_bounds__(256, 2)
void attn_kernel(const unsigned int* __restrict__ qb,
                 const unsigned int* __restrict__ kb,
                 const unsigned int* __restrict__ vb,
                 const int* __restrict__ adj,
                 const int* __restrict__ bond,
                 const float* __restrict__ table,
                 unsigned int* __restrict__ o)
{
    __shared__ unsigned short Kh[64][72], Kl[64][72];   // [key][hd]
    __shared__ unsigned short Vh[64][72], Vl[64][72];   // transposed: [hd][key]
    __shared__ unsigned short Ph[4][16][72], Pl[4][16][72];

    const int t = threadIdx.x, l = t & 63, w = t >> 6;
    const int bh = blockIdx.x;
    const int q0 = blockIdx.y * 64;
    const int b = bh / 12, h = bh - b * 12;

    const unsigned int* qp = qb + (size_t)bh * 512 * 64;
    const unsigned int* kp = kb + (size_t)bh * 512 * 64;
    const unsigned int* vp = vb + (size_t)bh * 512 * 64;

    const float t1 = table[1], t2 = table[2], t3 = table[3], t4 = table[4];

    // Q fragments (A-layout: row = lane&15, k = (lane>>4)*8 + i), hoisted
    short8 qh[2], ql[2];
    {
        int qrow = q0 + w*16 + (l & 15);
        #pragma unroll
        for (int ks = 0; ks < 2; ++ks){
            const unsigned int* p = qp + (size_t)qrow * 64 + ks*32 + (l >> 4) * 8;
            #pragma unroll
            for (int i = 0; i < 8; ++i){
                unsigned int u = p[i];
                qh[ks][i] = (short)(u & 0xffffu);
                ql[ks][i] = (short)(u >> 16);
            }
        }
    }

    f32x4 O[4] = {};
    float mrow[4] = {-3e38f, -3e38f, -3e38f, -3e38f};
    float lrow[4] = {0.f, 0.f, 0.f, 0.f};

    const int skey = t >> 2;
    const int sdg  = (t & 3) * 16;

    for (int kt = 0; kt < 8; ++kt){
        // stage K (copy) and V (transpose) into LDS
        {
            const unsigned int* kg = kp + (size_t)(kt*64 + skey) * 64 + sdg;
            const unsigned int* vg = vp + (size_t)(kt*64 + skey) * 64 + sdg;
            #pragma unroll
            for (int i = 0; i < 16; ++i){
                unsigned int u = kg[i];
                Kh[skey][sdg + i] = (unsigned short)(u & 0xffffu);
                Kl[skey][sdg + i] = (unsigned short)(u >> 16);
                unsigned int uv = vg[i];
                Vh[sdg + i][skey] = (unsigned short)(uv & 0xffffu);
                Vl[sdg + i][skey] = (unsigned short)(uv >> 16);
            }
        }
        __syncthreads();

        // S = Q K^T  (16 x 64 per wave)
        f32x4 S[4] = {};
        #pragma unroll
        for (int fc = 0; fc < 4; ++fc){
            #pragma unroll
            for (int ks = 0; ks < 2; ++ks){
                const int krow = fc*16 + (l & 15);
                const int kof  = ks*32 + (l >> 4) * 8;
                short8 kbh = *(const short8*)&Kh[krow][kof];
                short8 kbl = *(const short8*)&Kl[krow][kof];
                S[fc] = MFMA16(qh[ks], kbh, S[fc]);
                S[fc] = MFMA16(qh[ks], kbl, S[fc]);
                S[fc] = MFMA16(ql[ks], kbh, S[fc]);
            }
        }

        // bias + masked_fill(==0)
        float sv[4][4];
        #pragma unroll
        for (int fc = 0; fc < 4; ++fc){
            #pragma unroll
            for (int r = 0; r < 4; ++r){
                int rr = q0 + w*16 + ((l >> 4) << 2) + r;
                int cc = kt*64 + fc*16 + (l & 15);
                size_t idx = ((size_t)b * 512 + rr) * 512 + cc;
                int av = adj[idx];
                int bv = bond[idx];
                float bb2 = (bv == 1) ? t1 : (bv == 2) ? t2 : (bv == 3) ? t3 : (bv == 4) ? t4 : 0.0f;
                float val = S[fc][r] * 0.125f + (float)av + bb2;
                if (val == 0.0f) val = -1e9f;
                sv[fc][r] = val;
            }
        }

        // online softmax (rows live in 16-lane groups)
        float pvreg[4][4];
        #pragma unroll
        for (int r = 0; r < 4; ++r){
            float mt = fmaxf(fmaxf(sv[0][r], sv[1][r]), fmaxf(sv[2][r], sv[3][r]));
            #pragma unroll
            for (int off = 1; off < 16; off <<= 1)
                mt = fmaxf(mt, __shfl_xor(mt, off, 16));
            float mn = fmaxf(mrow[r], mt);
            float corr = __expf(mrow[r] - mn);
            float rs = 0.0f;
            #pragma unroll
            for (int fc = 0; fc < 4; ++fc){
                float p = __expf(sv[fc][r] - mn);
                pvreg[fc][r] = p;
                rs += p;
            }
            #pragma unroll
            for (int off = 1; off < 16; off <<= 1)
                rs += __shfl_xor(rs, off, 16);
            lrow[r] = lrow[r] * corr + rs;
            mrow[r] = mn;
            #pragma unroll
            for (int hf = 0; hf < 4; ++hf)
                O[hf][r] *= corr;
        }

        // P -> LDS (hi/lo)
        #pragma unroll
        for (int fc = 0; fc < 4; ++fc){
            #pragma unroll
            for (int r = 0; r < 4; ++r){
                unsigned short hh, ll;
                split2(pvreg[fc][r], hh, ll);
                Ph[w][((l >> 4) << 2) + r][fc*16 + (l & 15)] = hh;
                Pl[w][((l >> 4) << 2) + r][fc*16 + (l & 15)] = ll;
            }
        }

        // O += P @ V   (same-wave LDS RAW: compiler orders via lgkmcnt)
        #pragma unroll
        for (int ks = 0; ks < 2; ++ks){
            const int pof = ks*32 + (l >> 4) * 8;
            short8 pah = *(const short8*)&Ph[w][l & 15][pof];
            short8 pal = *(const short8*)&Pl[w][l & 15][pof];
            #pragma unroll
            for (int hf = 0; hf < 4; ++hf){
                short8 vbh = *(const short8*)&Vh[hf*16 + (l & 15)][pof];
                short8 vbl = *(const short8*)&Vl[hf*16 + (l & 15)][pof];
                O[hf] = MFMA16(pah, vbh, O[hf]);
                O[hf] = MFMA16(pah, vbl, O[hf]);
                O[hf] = MFMA16(pal, vbh, O[hf]);
            }
        }
        __syncthreads();
    }

    // epilogue: o (B,N,E) packed hi/lo uint
    #pragma unroll
    for (int r = 0; r < 4; ++r){
        float inv = 1.0f / lrow[r];
        int rr = q0 + w*16 + ((l >> 4) << 2) + r;
        #pragma unroll
        for (int hf = 0; hf < 4; ++hf){
            int col = h*64 + hf*16 + (l & 15);
            unsigned short hh, ll;
            split2(O[hf][r] * inv, hh, ll);
            o[((size_t)b * 512 + rr) * 768 + col] = (unsigned int)hh | ((unsigned int)ll << 16);
        }
    }
}

extern "C" void kernel_launch(void* const* d_in, const int* in_sizes, int n_in,
                              void* d_out, int out_size, void* d_ws, size_t ws_size,
                              hipStream_t stream)
{
    const float* x     = (const float*)d_in[0];
    const int*   adj   = (const int*)d_in[1];
    const int*   bond  = (const int*)d_in[2];
    const float* qkv_w = (const float*)d_in[4];
    const float* qkv_b = (const float*)d_in[5];
    const float* out_w = (const float*)d_in[6];
    const float* out_b = (const float*)d_in[7];
    const float* btab  = (const float*)d_in[8];
    float* out = (float*)d_out;

    const int QKV_ELEMS = 32 * 12 * 512 * 64;    // 12,582,912 per tensor
    unsigned int* q = (unsigned int*)d_ws;
    unsigned int* k = q + QKV_ELEMS;
    unsigned int* v = k + QKV_ELEMS;
    unsigned int* o = v + QKV_ELEMS;
    unsigned short* wqh = (unsigned short*)(o + QKV_ELEMS);
    unsigned short* wql = wqh + 2304 * 768;
    unsigned short* woh = wql + 2304 * 768;
    unsigned short* wol = woh + 768 * 768;

    dim3 blk(256);
    split_kernel<<<dim3((2304*768 + 255)/256), blk, 0, stream>>>(qkv_w, wqh, wql, 2304*768);
    split_kernel<<<dim3((768*768 + 255)/256),  blk, 0, stream>>>(out_w, woh, wol, 768*768);

    // QKV projection: (16384,768) @ (2304,768)^T -> packed q/k/v
    gemm_split<0,1><<<dim3(128, 18), blk, 81920, stream>>>(
        x, wqh, wql, qkv_b, 2304, 768, nullptr, q, k, v);

    // fused attention
    attn_kernel<<<dim3(384, 8), blk, 0, stream>>>(q, k, v, adj, bond, btab, o);

    // output projection: (16384,768) @ (768,768)^T -> d_out fp32
    gemm_split<1,0><<<dim3(128, 6), blk, 81920, stream>>>(
        o, woh, wol, out_b, 768, 768, out, nullptr, nullptr, nullptr ? nullptr : nullptr);
}

// Round 2
// 527.522 us; speedup vs baseline: 1.3862x; 1.3862x over previous
//
#include <hip/hip_runtime.h>
#include <hip/hip_bf16.h>

typedef __attribute__((ext_vector_type(8))) short short8;
typedef __attribute__((ext_vector_type(8))) unsigned short ushort8;
typedef __attribute__((ext_vector_type(4))) unsigned short ushort4v;
typedef __attribute__((ext_vector_type(4))) float f32x4;
typedef __attribute__((ext_vector_type(4))) unsigned int uint4v;

#define MFMA16(a,b,c) __builtin_amdgcn_mfma_f32_16x16x32_bf16((a),(b),(c),0,0,0)

__device__ __forceinline__ unsigned short f2bf(float f){
    union { float f; unsigned int u; } c; c.f = f;
    unsigned int u = c.u;
    u = (u + 0x7fffu + ((u >> 16) & 1u)) >> 16;
    return (unsigned short)u;
}
__device__ __forceinline__ float bf2f(unsigned short s){
    union { unsigned int u; float f; } c; c.u = ((unsigned int)s) << 16;
    return c.f;
}
__device__ __forceinline__ void split2(float f, unsigned short &h, unsigned short &l){
    h = f2bf(f);
    l = f2bf(f - bf2f(h));
}

// unpack 8 packed uints (hi|lo<<16) into hi/lo bf16 short8 fragments
__device__ __forceinline__ void unpack8(uint4v u0, uint4v u1, short8& hi, short8& lo){
    uint4v h, l;
    h[0] = (u0[0] & 0xffffu) | (u0[1] << 16);
    h[1] = (u0[2] & 0xffffu) | (u0[3] << 16);
    h[2] = (u1[0] & 0xffffu) | (u1[1] << 16);
    h[3] = (u1[2] & 0xffffu) | (u1[3] << 16);
    l[0] = (u0[0] >> 16) | (u0[1] & 0xffff0000u);
    l[1] = (u0[2] >> 16) | (u0[3] & 0xffff0000u);
    l[2] = (u1[0] >> 16) | (u1[1] & 0xffff0000u);
    l[3] = (u1[2] >> 16) | (u1[3] & 0xffff0000u);
    hi = __builtin_bit_cast(short8, h);
    lo = __builtin_bit_cast(short8, l);
}

// ---------------- weight pre-split (fp32 -> bf16 hi/lo planes) ----------------
__global__ void split_kernel(const float* __restrict__ in, unsigned short* __restrict__ h,
                             unsigned short* __restrict__ l, int n){
    int i = blockIdx.x * 256 + threadIdx.x;
    if (i < n){
        unsigned short hh, ll;
        split2(in[i], hh, ll);
        h[i] = hh; l[i] = ll;
    }
}

// ---------------- split-bf16 GEMM: C = A @ W^T + bias ----------------
template<int AMODE, int EMODE>
__global__ __launch_bounds__(256, 2)
void gemm_split(const void* __restrict__ Avoid,
                const unsigned short* __restrict__ Wh, const unsigned short* __restrict__ Wl,
                const float* __restrict__ bias, int N, int K,
                float* __restrict__ C,
                unsigned int* __restrict__ qo, unsigned int* __restrict__ ko,
                unsigned int* __restrict__ vo)
{
    extern __shared__ unsigned short lds[];
    constexpr int LDT = 40;
    constexpr int TSZ = 128 * LDT;
    unsigned short* Ah = lds;
    unsigned short* Al = lds + 2 * TSZ;
    unsigned short* Bh = lds + 4 * TSZ;
    unsigned short* Bl = lds + 6 * TSZ;

    const int t = threadIdx.x;
    const int l = t & 63, w = t >> 6;
    const int wr = (w >> 1) * 64, wc = (w & 1) * 64;
    const int m0 = blockIdx.x * 128, j0 = blockIdx.y * 128;
    const int NT = K >> 5;

    const int a_r = t >> 3, a_c = (t & 7) * 4;
    const int b_r = t >> 2, b_c = (t & 3) * 8;

    f32x4  raf[4];
    uint4v rau[4];
    ushort8 rbh[2], rbl[2];
    f32x4 acc[4][4] = {};

    auto gload = [&](int kt){
        if constexpr (AMODE == 0){
            const float* A = (const float*)Avoid;
            #pragma unroll
            for (int i = 0; i < 4; ++i)
                raf[i] = *(const f32x4*)(A + (size_t)(m0 + i*32 + a_r)*K + kt*32 + a_c);
        } else {
            const unsigned int* A = (const unsigned int*)Avoid;
            #pragma unroll
            for (int i = 0; i < 4; ++i)
                rau[i] = *(const uint4v*)(A + (size_t)(m0 + i*32 + a_r)*K + kt*32 + a_c);
        }
        #pragma unroll
        for (int i = 0; i < 2; ++i){
            int row = i*64 + b_r;
            rbh[i] = *(const ushort8*)(Wh + (size_t)(j0 + row)*K + kt*32 + b_c);
            rbl[i] = *(const ushort8*)(Wl + (size_t)(j0 + row)*K + kt*32 + b_c);
        }
    };
    auto lstore = [&](int buf){
        #pragma unroll
        for (int i = 0; i < 4; ++i){
            int base = buf*TSZ + (i*32 + a_r)*LDT + a_c;
            unsigned short h0,h1,h2,h3,l0,l1,l2,l3;
            if constexpr (AMODE == 0){
                split2(raf[i][0], h0, l0); split2(raf[i][1], h1, l1);
                split2(raf[i][2], h2, l2); split2(raf[i][3], h3, l3);
            } else {
                h0 = (unsigned short)(rau[i][0] & 0xffffu); l0 = (unsigned short)(rau[i][0] >> 16);
                h1 = (unsigned short)(rau[i][1] & 0xffffu); l1 = (unsigned short)(rau[i][1] >> 16);
                h2 = (unsigned short)(rau[i][2] & 0xffffu); l2 = (unsigned short)(rau[i][2] >> 16);
                h3 = (unsigned short)(rau[i][3] & 0xffffu); l3 = (unsigned short)(rau[i][3] >> 16);
            }
            ushort4v hv = {h0,h1,h2,h3}, lv = {l0,l1,l2,l3};
            *(ushort4v*)(Ah + base) = hv;
            *(ushort4v*)(Al + base) = lv;
        }
        #pragma unroll
        for (int i = 0; i < 2; ++i){
            int base = buf*TSZ + (i*64 + b_r)*LDT + b_c;
            *(ushort8*)(Bh + base) = rbh[i];
            *(ushort8*)(Bl + base) = rbl[i];
        }
    };

    gload(0);
    lstore(0);
    __syncthreads();
    int cur = 0;

    for (int kt = 0; kt < NT; ++kt){
        if (kt + 1 < NT) gload(kt + 1);

        const int ko_ = (l >> 4) * 8;
        short8 afh[4], afl[4], bfh[4], bfl[4];
        #pragma unroll
        for (int f = 0; f < 4; ++f){
            int arow = wr + f*16 + (l & 15);
            int brow = wc + f*16 + (l & 15);
            afh[f] = *(const short8*)(Ah + cur*TSZ + arow*LDT + ko_);
            afl[f] = *(const short8*)(Al + cur*TSZ + arow*LDT + ko_);
            bfh[f] = *(const short8*)(Bh + cur*TSZ + brow*LDT + ko_);
            bfl[f] = *(const short8*)(Bl + cur*TSZ + brow*LDT + ko_);
        }
        #pragma unroll
        for (int fr = 0; fr < 4; ++fr)
            #pragma unroll
            for (int fc = 0; fc < 4; ++fc){
                acc[fr][fc] = MFMA16(afh[fr], bfh[fc], acc[fr][fc]);
                acc[fr][fc] = MFMA16(afh[fr], bfl[fc], acc[fr][fc]);
                acc[fr][fc] = MFMA16(afl[fr], bfh[fc], acc[fr][fc]);
            }

        if (kt + 1 < NT) lstore(cur ^ 1);
        __syncthreads();
        cur ^= 1;
    }

    #pragma unroll
    for (int fr = 0; fr < 4; ++fr){
        #pragma unroll
        for (int fc = 0; fc < 4; ++fc){
            #pragma unroll
            for (int r = 0; r < 4; ++r){
                int m = m0 + wr + fr*16 + ((l >> 4) << 2) + r;
                int j = j0 + wc + fc*16 + (l & 15);
                float val = acc[fr][fc][r] + bias[j];
                if constexpr (EMODE == 0){
                    C[(size_t)m * N + j] = val;
                } else {
                    int sec = j / 768;
                    int off = j - sec * 768;
                    int head = off >> 6, d = off & 63;
                    int bb = m >> 9, n = m & 511;
                    unsigned short hh, ll; split2(val, hh, ll);
                    unsigned int packed = (unsigned int)hh | ((unsigned int)ll << 16);
                    if (sec == 2) {
                        // V written TRANSPOSED: (B, h, hd, N) so attention's PV
                        // B-operand reads are row reads (k = key contiguous).
                        vo[(((size_t)bb * 12 + head) * 64 + d) * 512 + n] = packed;
                    } else {
                        unsigned int* dst = (sec == 0) ? qo : ko;
                        dst[(((size_t)bb * 12 + head) * 512 + n) * 64 + d] = packed;
                    }
                }
            }
        }
    }
}

// ---------------- fused flash attention (split-bf16 MFMA, packed LDS) ----------------
// grid (384 = b*12+h, 8 q-tiles of 64). 256 threads = 4 waves; wave owns 16 q-rows.
__global__ __launch_bounds__(256, 3)
void attn_kernel(const unsigned int* __restrict__ qb,
                 const unsigned int* __restrict__ kb,
                 const unsigned int* __restrict__ vtb,   // (B,h,hd,N) packed
                 const int* __restrict__ adj,
                 const int* __restrict__ bond,
                 const float* __restrict__ table,
                 unsigned int* __restrict__ o)
{
    __shared__ unsigned int Kt[64 * 64];      // [key][d]   packed, XOR-swizzled rows
    __shared__ unsigned int Vt[64 * 64];      // [hd][key]  packed, XOR-swizzled rows
    __shared__ unsigned int Pt[4][16 * 68];   // per-wave P [q][key], pad 68 (2-way free)

    const int t = threadIdx.x, l = t & 63, w = t >> 6;
    const int c = l & 15, g = l >> 4;
    const int bh = blockIdx.x, q0 = blockIdx.y * 64;
    const int b = bh / 12, h = bh - b * 12;

    const unsigned int* qp  = qb  + (size_t)bh * 512 * 64;
    const unsigned int* kp  = kb  + (size_t)bh * 512 * 64;
    const unsigned int* vtp = vtb + (size_t)bh * 64 * 512;

    const float t1 = table[1], t2 = table[2], t3 = table[3], t4 = table[4];

    // hoisted Q fragments (A-operand: row = lane&15 over q, k = g*8.. over d)
    short8 qh[2], ql[2];
    {
        int qrow = q0 + w*16 + c;
        #pragma unroll
        for (int ks = 0; ks < 2; ++ks){
            const unsigned int* p = qp + (size_t)qrow * 64 + ks*32 + g*8;
            uint4v u0 = *(const uint4v*)p;
            uint4v u1 = *(const uint4v*)(p + 4);
            unpack8(u0, u1, qh[ks], ql[ks]);
        }
    }

    f32x4 O[4] = {};
    float mrow[4] = {-3e38f, -3e38f, -3e38f, -3e38f};
    float lrow[4] = {0.f, 0.f, 0.f, 0.f};

    const int srow = t >> 2;           // staging row 0..63
    const int scol = (t & 3) * 16;     // staging col (uints)
    const int ssw  = (srow & 7) << 4;  // byte swizzle for this row

    // swizzled b128 LDS fragment read + register unpack
    auto rdfrag = [&](const unsigned int* base, int row, int colb, short8& hi, short8& lo){
        int sw = (row & 7) << 4;
        const char* p = (const char*)base + row*256;
        uint4v u0 = *(const uint4v*)(p + ((colb     ) ^ sw));
        uint4v u1 = *(const uint4v*)(p + ((colb + 16) ^ sw));
        unpack8(u0, u1, hi, lo);
    };

    for (int kt = 0; kt < 8; ++kt){
        // ---- stage K and V^T tiles (packed, vector, swizzled) ----
        {
            const unsigned int* kg = kp  + (size_t)(kt*64 + srow) * 64 + scol;
            const unsigned int* vg = vtp + (size_t)srow * 512 + kt*64 + scol;
            #pragma unroll
            for (int i = 0; i < 4; ++i){
                uint4v a  = *(const uint4v*)(kg + 4*i);
                uint4v bx = *(const uint4v*)(vg + 4*i);
                int cb = (scol + 4*i) * 4;
                *(uint4v*)((char*)Kt + srow*256 + (cb ^ ssw)) = a;
                *(uint4v*)((char*)Vt + srow*256 + (cb ^ ssw)) = bx;
            }
        }
        __syncthreads();

        // ---- issue adj/bond loads early (hide latency under MFMA) ----
        int av[4][4], bv[4][4];
        #pragma unroll
        for (int fc = 0; fc < 4; ++fc){
            #pragma unroll
            for (int r = 0; r < 4; ++r){
                int rr = q0 + w*16 + g*4 + r;
                int cc = kt*64 + fc*16 + c;
                size_t idx = ((size_t)b * 512 + rr) * 512 + cc;
                av[fc][r] = adj[idx];
                bv[fc][r] = bond[idx];
            }
        }

        // ---- S = Q K^T ----
        f32x4 S[4] = {};
        #pragma unroll
        for (int fc = 0; fc < 4; ++fc){
            #pragma unroll
            for (int ks = 0; ks < 2; ++ks){
                short8 kbh, kbl;
                rdfrag(Kt, fc*16 + c, ks*128 + g*32, kbh, kbl);
                S[fc] = MFMA16(qh[ks], kbh, S[fc]);
                S[fc] = MFMA16(qh[ks], kbl, S[fc]);
                S[fc] = MFMA16(ql[ks], kbh, S[fc]);
            }
        }

        // ---- bias + masked_fill(==0) ----
        float sv[4][4];
        #pragma unroll
        for (int fc = 0; fc < 4; ++fc){
            #pragma unroll
            for (int r = 0; r < 4; ++r){
                int bb2 = bv[fc][r];
                float bias2 = (bb2 == 1) ? t1 : (bb2 == 2) ? t2 : (bb2 == 3) ? t3 : (bb2 == 4) ? t4 : 0.0f;
                float val = S[fc][r] * 0.125f + (float)av[fc][r] + bias2;
                if (val == 0.0f) val = -1e9f;
                sv[fc][r] = val;
            }
        }

        // ---- online softmax (rows in 16-lane groups) ----
        float pvreg[4][4];
        #pragma unroll
        for (int r = 0; r < 4; ++r){
            float mt = fmaxf(fmaxf(sv[0][r], sv[1][r]), fmaxf(sv[2][r], sv[3][r]));
            #pragma unroll
            for (int off = 1; off < 16; off <<= 1)
                mt = fmaxf(mt, __shfl_xor(mt, off, 16));
            float mn = fmaxf(mrow[r], mt);
            float corr = __expf(mrow[r] - mn);
            float rs = 0.0f;
            #pragma unroll
            for (int fc = 0; fc < 4; ++fc){
                float p = __expf(sv[fc][r] - mn);
                pvreg[fc][r] = p;
                rs += p;
            }
            #pragma unroll
            for (int off = 1; off < 16; off <<= 1)
                rs += __shfl_xor(rs, off, 16);
            lrow[r] = lrow[r] * corr + rs;
            mrow[r] = mn;
            #pragma unroll
            for (int hf = 0; hf < 4; ++hf)
                O[hf][r] *= corr;
        }

        // ---- P -> LDS packed (same-wave region, no barrier needed) ----
        #pragma unroll
        for (int fc = 0; fc < 4; ++fc){
            #pragma unroll
            for (int r = 0; r < 4; ++r){
                unsigned short hh, ll;
                split2(pvreg[fc][r], hh, ll);
                Pt[w][(g*4 + r)*68 + fc*16 + c] = (unsigned int)hh | ((unsigned int)ll << 16);
            }
        }

        // ---- O += P @ V ----
        #pragma unroll
        for (int ks = 0; ks < 2; ++ks){
            const unsigned int* pp = &Pt[w][c*68 + ks*32 + g*8];
            uint4v pu0 = *(const uint4v*)pp;
            uint4v pu1 = *(const uint4v*)(pp + 4);
            short8 pah, pal;
            unpack8(pu0, pu1, pah, pal);
            #pragma unroll
            for (int hf = 0; hf < 4; ++hf){
                short8 vbh, vbl;
                rdfrag(Vt, hf*16 + c, ks*128 + g*32, vbh, vbl);
                O[hf] = MFMA16(pah, vbh, O[hf]);
                O[hf] = MFMA16(pah, vbl, O[hf]);
                O[hf] = MFMA16(pal, vbh, O[hf]);
            }
        }
        __syncthreads();
    }

    // ---- epilogue: o (B,N,E) packed hi/lo uint ----
    #pragma unroll
    for (int r = 0; r < 4; ++r){
        float inv = 1.0f / lrow[r];
        int rr = q0 + w*16 + g*4 + r;
        #pragma unroll
        for (int hf = 0; hf < 4; ++hf){
            int col = h*64 + hf*16 + c;
            unsigned short hh, ll;
            split2(O[hf][r] * inv, hh, ll);
            o[((size_t)b * 512 + rr) * 768 + col] = (unsigned int)hh | ((unsigned int)ll << 16);
        }
    }
}

extern "C" void kernel_launch(void* const* d_in, const int* in_sizes, int n_in,
                              void* d_out, int out_size, void* d_ws, size_t ws_size,
                              hipStream_t stream)
{
    const float* x     = (const float*)d_in[0];
    const int*   adj   = (const int*)d_in[1];
    const int*   bond  = (const int*)d_in[2];
    const float* qkv_w = (const float*)d_in[4];
    const float* qkv_b = (const float*)d_in[5];
    const float* out_w = (const float*)d_in[6];
    const float* out_b = (const float*)d_in[7];
    const float* btab  = (const float*)d_in[8];
    float* out = (float*)d_out;

    const int QKV_ELEMS = 32 * 12 * 512 * 64;
    unsigned int* q  = (unsigned int*)d_ws;
    unsigned int* k  = q + QKV_ELEMS;
    unsigned int* vt = k + QKV_ELEMS;          // (B,h,hd,N) packed
    unsigned int* o  = vt + QKV_ELEMS;
    unsigned short* wqh = (unsigned short*)(o + QKV_ELEMS);
    unsigned short* wql = wqh + 2304 * 768;
    unsigned short* woh = wql + 2304 * 768;
    unsigned short* wol = woh + 768 * 768;

    dim3 blk(256);
    split_kernel<<<dim3((2304*768 + 255)/256), blk, 0, stream>>>(qkv_w, wqh, wql, 2304*768);
    split_kernel<<<dim3((768*768 + 255)/256),  blk, 0, stream>>>(out_w, woh, wol, 768*768);

    gemm_split<0,1><<<dim3(128, 18), blk, 81920, stream>>>(
        x, wqh, wql, qkv_b, 2304, 768, nullptr, q, k, vt);

    attn_kernel<<<dim3(384, 8), blk, 0, stream>>>(q, k, vt, adj, bond, btab, o);

    gemm_split<1,0><<<dim3(128, 6), blk, 81920, stream>>>(
        o, woh, wol, out_b, 768, 768, out, nullptr, nullptr, nullptr);
}

// Round 3
// 477.980 us; speedup vs baseline: 1.5299x; 1.1036x over previous
//
#include <hip/hip_runtime.h>
#include <hip/hip_bf16.h>

typedef __attribute__((ext_vector_type(8))) short short8;
typedef __attribute__((ext_vector_type(8))) unsigned short ushort8;
typedef __attribute__((ext_vector_type(4))) unsigned short ushort4v;
typedef __attribute__((ext_vector_type(4))) float f32x4;
typedef __attribute__((ext_vector_type(4))) unsigned int uint4v;
typedef __attribute__((ext_vector_type(2))) unsigned int uint2v;
typedef __attribute__((ext_vector_type(4))) int int4v;

#define MFMA16(a,b,c) __builtin_amdgcn_mfma_f32_16x16x32_bf16((a),(b),(c),0,0,0)

// RNE fp32->bf16 (used only in one-time weight pre-split)
__device__ __forceinline__ unsigned short f2bf(float f){
    union { float f; unsigned int u; } c; c.f = f;
    unsigned int u = c.u;
    u = (u + 0x7fffu + ((u >> 16) & 1u)) >> 16;
    return (unsigned short)u;
}
__device__ __forceinline__ float bf2f(unsigned short s){
    union { unsigned int u; float f; } c; c.u = ((unsigned int)s) << 16;
    return c.f;
}
__device__ __forceinline__ void split2(float f, unsigned short &h, unsigned short &l){
    h = f2bf(f);
    l = f2bf(f - bf2f(h));
}

// truncation split, packed (hi | lo<<16): 3 VALU (and, sub, perm)
__device__ __forceinline__ unsigned int pack_split(float f){
    unsigned int u = __builtin_bit_cast(unsigned int, f);
    float hi = __builtin_bit_cast(float, u & 0xffff0000u);
    unsigned int rem = __builtin_bit_cast(unsigned int, f - hi);
    return __builtin_amdgcn_perm(rem, u, 0x07060302u);
}

// unpack 8 packed uints (hi|lo<<16) -> hi/lo bf16 short8 fragments: 8 v_perm
__device__ __forceinline__ void unpack8(uint4v u0, uint4v u1, short8& hi, short8& lo){
    uint4v h, l;
    h[0] = __builtin_amdgcn_perm(u0[1], u0[0], 0x05040100u);
    h[1] = __builtin_amdgcn_perm(u0[3], u0[2], 0x05040100u);
    h[2] = __builtin_amdgcn_perm(u1[1], u1[0], 0x05040100u);
    h[3] = __builtin_amdgcn_perm(u1[3], u1[2], 0x05040100u);
    l[0] = __builtin_amdgcn_perm(u0[1], u0[0], 0x07060302u);
    l[1] = __builtin_amdgcn_perm(u0[3], u0[2], 0x07060302u);
    l[2] = __builtin_amdgcn_perm(u1[1], u1[0], 0x07060302u);
    l[3] = __builtin_amdgcn_perm(u1[3], u1[2], 0x07060302u);
    hi = __builtin_bit_cast(short8, h);
    lo = __builtin_bit_cast(short8, l);
}

// ---------------- weight pre-split (fp32 -> bf16 hi/lo planes, RNE) ----------------
__global__ void split_kernel(const float* __restrict__ in, unsigned short* __restrict__ h,
                             unsigned short* __restrict__ l, int n){
    int i = blockIdx.x * 256 + threadIdx.x;
    if (i < n){
        unsigned short hh, ll;
        split2(in[i], hh, ll);
        h[i] = hh; l[i] = ll;
    }
}

// ---------------- combined bias precompute: biasC = adj + table[bond] ----------------
__global__ void bias_kernel(const int* __restrict__ adj, const int* __restrict__ bond,
                            const float* __restrict__ table, float* __restrict__ biasC, int n4){
    int i = blockIdx.x * 256 + threadIdx.x;
    if (i >= n4) return;
    int4v a  = ((const int4v*)adj)[i];
    int4v bd = ((const int4v*)bond)[i];
    const float t1 = table[1], t2 = table[2], t3 = table[3], t4 = table[4];
    f32x4 o;
    #pragma unroll
    for (int j = 0; j < 4; ++j){
        int bv = bd[j];
        float tb = (bv == 1) ? t1 : (bv == 2) ? t2 : (bv == 3) ? t3 : (bv == 4) ? t4 : 0.0f;
        o[j] = (float)a[j] + tb;           // padding_idx=0 -> 0 enforced here
    }
    ((f32x4*)biasC)[i] = o;
}

// ---------------- split-bf16 GEMM: C = A @ W^T + bias ----------------
// 1D grid, XCD-chunked: xcd = lin&7 owns MTILES/8 row-tiles, iterating NCB col-tiles
// consecutively so the A row-panel stays L2-resident.
template<int AMODE, int EMODE>
__global__ __launch_bounds__(256, 2)
void gemm_split(const void* __restrict__ Avoid,
                const unsigned short* __restrict__ Wh, const unsigned short* __restrict__ Wl,
                const float* __restrict__ bias, int N, int K, int NCB, int ROWS_PER_XCD,
                float* __restrict__ C,
                unsigned int* __restrict__ qo, unsigned int* __restrict__ ko,
                unsigned int* __restrict__ vo)
{
    extern __shared__ unsigned short lds[];
    constexpr int LDT = 40;
    constexpr int TSZ = 128 * LDT;
    unsigned short* Ah = lds;
    unsigned short* Al = lds + 2 * TSZ;
    unsigned short* Bh = lds + 4 * TSZ;
    unsigned short* Bl = lds + 6 * TSZ;

    const int lin = blockIdx.x;
    const int xcd = lin & 7, idx = lin >> 3;
    const int rowL = idx / NCB, colT = idx - rowL * NCB;
    const int m0 = (xcd * ROWS_PER_XCD + rowL) * 128;
    const int j0 = colT * 128;

    const int t = threadIdx.x;
    const int l = t & 63, w = t >> 6;
    const int wr = (w >> 1) * 64, wc = (w & 1) * 64;
    const int NT = K >> 5;

    const int a_r = t >> 3, a_c = (t & 7) * 4;
    const int b_r = t >> 2, b_c = (t & 3) * 8;

    f32x4  raf[4];
    uint4v rau[4];
    ushort8 rbh[2], rbl[2];
    f32x4 acc[4][4] = {};

    auto gload = [&](int kt){
        if constexpr (AMODE == 0){
            const float* A = (const float*)Avoid;
            #pragma unroll
            for (int i = 0; i < 4; ++i)
                raf[i] = *(const f32x4*)(A + (size_t)(m0 + i*32 + a_r)*K + kt*32 + a_c);
        } else {
            const unsigned int* A = (const unsigned int*)Avoid;
            #pragma unroll
            for (int i = 0; i < 4; ++i)
                rau[i] = *(const uint4v*)(A + (size_t)(m0 + i*32 + a_r)*K + kt*32 + a_c);
        }
        #pragma unroll
        for (int i = 0; i < 2; ++i){
            int row = i*64 + b_r;
            rbh[i] = *(const ushort8*)(Wh + (size_t)(j0 + row)*K + kt*32 + b_c);
            rbl[i] = *(const ushort8*)(Wl + (size_t)(j0 + row)*K + kt*32 + b_c);
        }
    };
    auto lstore = [&](int buf){
        #pragma unroll
        for (int i = 0; i < 4; ++i){
            int base = buf*TSZ + (i*32 + a_r)*LDT + a_c;
            uint2v hv, lv;
            if constexpr (AMODE == 0){
                unsigned int ub[4], rb[4];
                #pragma unroll
                for (int j = 0; j < 4; ++j){
                    ub[j] = __builtin_bit_cast(unsigned int, raf[i][j]);
                    float hf = __builtin_bit_cast(float, ub[j] & 0xffff0000u);
                    rb[j] = __builtin_bit_cast(unsigned int, raf[i][j] - hf);
                }
                hv[0] = __builtin_amdgcn_perm(ub[1], ub[0], 0x07060302u);
                hv[1] = __builtin_amdgcn_perm(ub[3], ub[2], 0x07060302u);
                lv[0] = __builtin_amdgcn_perm(rb[1], rb[0], 0x07060302u);
                lv[1] = __builtin_amdgcn_perm(rb[3], rb[2], 0x07060302u);
            } else {
                hv[0] = __builtin_amdgcn_perm(rau[i][1], rau[i][0], 0x05040100u);
                hv[1] = __builtin_amdgcn_perm(rau[i][3], rau[i][2], 0x05040100u);
                lv[0] = __builtin_amdgcn_perm(rau[i][1], rau[i][0], 0x07060302u);
                lv[1] = __builtin_amdgcn_perm(rau[i][3], rau[i][2], 0x07060302u);
            }
            *(ushort4v*)(Ah + base) = __builtin_bit_cast(ushort4v, hv);
            *(ushort4v*)(Al + base) = __builtin_bit_cast(ushort4v, lv);
        }
        #pragma unroll
        for (int i = 0; i < 2; ++i){
            int base = buf*TSZ + (i*64 + b_r)*LDT + b_c;
            *(ushort8*)(Bh + base) = rbh[i];
            *(ushort8*)(Bl + base) = rbl[i];
        }
    };

    gload(0);
    lstore(0);
    __syncthreads();
    int cur = 0;

    for (int kt = 0; kt < NT; ++kt){
        if (kt + 1 < NT) gload(kt + 1);

        const int ko_ = (l >> 4) * 8;
        short8 afh[4], afl[4], bfh[4], bfl[4];
        #pragma unroll
        for (int f = 0; f < 4; ++f){
            int arow = wr + f*16 + (l & 15);
            int brow = wc + f*16 + (l & 15);
            afh[f] = *(const short8*)(Ah + cur*TSZ + arow*LDT + ko_);
            afl[f] = *(const short8*)(Al + cur*TSZ + arow*LDT + ko_);
            bfh[f] = *(const short8*)(Bh + cur*TSZ + brow*LDT + ko_);
            bfl[f] = *(const short8*)(Bl + cur*TSZ + brow*LDT + ko_);
        }
        __builtin_amdgcn_s_setprio(1);
        #pragma unroll
        for (int fr = 0; fr < 4; ++fr)
            #pragma unroll
            for (int fc = 0; fc < 4; ++fc){
                acc[fr][fc] = MFMA16(afh[fr], bfh[fc], acc[fr][fc]);
                acc[fr][fc] = MFMA16(afh[fr], bfl[fc], acc[fr][fc]);
                acc[fr][fc] = MFMA16(afl[fr], bfh[fc], acc[fr][fc]);
            }
        __builtin_amdgcn_s_setprio(0);

        if (kt + 1 < NT) lstore(cur ^ 1);
        __syncthreads();
        cur ^= 1;
    }

    #pragma unroll
    for (int fr = 0; fr < 4; ++fr){
        #pragma unroll
        for (int fc = 0; fc < 4; ++fc){
            #pragma unroll
            for (int r = 0; r < 4; ++r){
                int m = m0 + wr + fr*16 + ((l >> 4) << 2) + r;
                int j = j0 + wc + fc*16 + (l & 15);
                float val = acc[fr][fc][r] + bias[j];
                if constexpr (EMODE == 0){
                    C[(size_t)m * N + j] = val;
                } else {
                    int sec = j / 768;
                    int off = j - sec * 768;
                    int head = off >> 6, d = off & 63;
                    int bb = m >> 9, n = m & 511;
                    unsigned int packed = pack_split(val);
                    if (sec == 2) {
                        // V written TRANSPOSED: (B, h, hd, N)
                        vo[(((size_t)bb * 12 + head) * 64 + d) * 512 + n] = packed;
                    } else {
                        unsigned int* dst = (sec == 0) ? qo : ko;
                        dst[(((size_t)bb * 12 + head) * 512 + n) * 64 + d] = packed;
                    }
                }
            }
        }
    }
}

// ---------------- fused flash attention (split-bf16 MFMA, packed LDS) ----------------
// 1D grid 3072, XCD-chunked: xcd owns 4 whole batches (biasC slab L2-resident).
__global__ __launch_bounds__(256, 3)
void attn_kernel(const unsigned int* __restrict__ qb,
                 const unsigned int* __restrict__ kb,
                 const unsigned int* __restrict__ vtb,   // (B,h,hd,N) packed
                 const float* __restrict__ biasC,        // (B,N,N) adj + bond_bias
                 unsigned int* __restrict__ o)
{
    __shared__ unsigned int Kt[64 * 64];      // [key][d]   packed, XOR-swizzled rows
    __shared__ unsigned int Vt[64 * 64];      // [hd][key]  packed, XOR-swizzled rows
    __shared__ unsigned int Pt[4][16 * 68];   // per-wave P [q][key]

    const int lin = blockIdx.x;
    const int xcd = lin & 7, m_ = lin >> 3;
    const int bgrp = m_ / 96, r_ = m_ - bgrp * 96;
    const int b = (bgrp << 3) | xcd;
    const int h = r_ >> 3, qt = r_ & 7;
    const int bh = b * 12 + h, q0 = qt * 64;

    const int t = threadIdx.x, l = t & 63, w = t >> 6;
    const int c = l & 15, g = l >> 4;

    const unsigned int* qp  = qb  + (size_t)bh * 512 * 64;
    const unsigned int* kp  = kb  + (size_t)bh * 512 * 64;
    const unsigned int* vtp = vtb + (size_t)bh * 64 * 512;

    // hoisted Q fragments
    short8 qh[2], ql[2];
    {
        int qrow = q0 + w*16 + c;
        #pragma unroll
        for (int ks = 0; ks < 2; ++ks){
            const unsigned int* p = qp + (size_t)qrow * 64 + ks*32 + g*8;
            uint4v u0 = *(const uint4v*)p;
            uint4v u1 = *(const uint4v*)(p + 4);
            unpack8(u0, u1, qh[ks], ql[ks]);
        }
    }

    f32x4 O[4] = {};
    float mrow[4] = {-3e38f, -3e38f, -3e38f, -3e38f};
    float lrow[4] = {0.f, 0.f, 0.f, 0.f};

    const int srow = t >> 2;
    const int scol = (t & 3) * 16;
    const int ssw  = (srow & 7) << 4;

    auto rdfrag = [&](const unsigned int* base, int row, int colb, short8& hi, short8& lo){
        int sw = (row & 7) << 4;
        const char* p = (const char*)base + row*256;
        uint4v u0 = *(const uint4v*)(p + ((colb     ) ^ sw));
        uint4v u1 = *(const uint4v*)(p + ((colb + 16) ^ sw));
        unpack8(u0, u1, hi, lo);
    };

    for (int kt = 0; kt < 8; ++kt){
        // ---- stage K and V^T tiles ----
        {
            const unsigned int* kg = kp  + (size_t)(kt*64 + srow) * 64 + scol;
            const unsigned int* vg = vtp + (size_t)srow * 512 + kt*64 + scol;
            #pragma unroll
            for (int i = 0; i < 4; ++i){
                uint4v a  = *(const uint4v*)(kg + 4*i);
                uint4v bx = *(const uint4v*)(vg + 4*i);
                int cb = (scol + 4*i) * 4;
                *(uint4v*)((char*)Kt + srow*256 + (cb ^ ssw)) = a;
                *(uint4v*)((char*)Vt + srow*256 + (cb ^ ssw)) = bx;
            }
        }
        __syncthreads();

        // ---- combined bias loads (issue early) ----
        float bia[4][4];
        #pragma unroll
        for (int fc = 0; fc < 4; ++fc){
            #pragma unroll
            for (int r = 0; r < 4; ++r){
                int rr = q0 + w*16 + g*4 + r;
                int cc = kt*64 + fc*16 + c;
                bia[fc][r] = biasC[((size_t)b * 512 + rr) * 512 + cc];
            }
        }

        // ---- S = Q K^T ----
        f32x4 S[4] = {};
        #pragma unroll
        for (int fc = 0; fc < 4; ++fc){
            short8 kbh0, kbl0, kbh1, kbl1;
            rdfrag(Kt, fc*16 + c,       g*32, kbh0, kbl0);
            rdfrag(Kt, fc*16 + c, 128 + g*32, kbh1, kbl1);
            __builtin_amdgcn_s_setprio(1);
            S[fc] = MFMA16(qh[0], kbh0, S[fc]);
            S[fc] = MFMA16(qh[0], kbl0, S[fc]);
            S[fc] = MFMA16(ql[0], kbh0, S[fc]);
            S[fc] = MFMA16(qh[1], kbh1, S[fc]);
            S[fc] = MFMA16(qh[1], kbl1, S[fc]);
            S[fc] = MFMA16(ql[1], kbh1, S[fc]);
            __builtin_amdgcn_s_setprio(0);
        }

        // ---- bias + masked_fill(==0) ----
        float sv[4][4];
        #pragma unroll
        for (int fc = 0; fc < 4; ++fc){
            #pragma unroll
            for (int r = 0; r < 4; ++r){
                float val = fmaf(S[fc][r], 0.125f, bia[fc][r]);
                if (val == 0.0f) val = -1e9f;
                sv[fc][r] = val;
            }
        }

        // ---- online softmax (rows in 16-lane groups) ----
        float pvreg[4][4];
        #pragma unroll
        for (int r = 0; r < 4; ++r){
            float mt = fmaxf(fmaxf(sv[0][r], sv[1][r]), fmaxf(sv[2][r], sv[3][r]));
            #pragma unroll
            for (int off = 1; off < 16; off <<= 1)
                mt = fmaxf(mt, __shfl_xor(mt, off, 16));
            float mn = fmaxf(mrow[r], mt);
            float corr = __expf(mrow[r] - mn);
            float rs = 0.0f;
            #pragma unroll
            for (int fc = 0; fc < 4; ++fc){
                float p = __expf(sv[fc][r] - mn);
                pvreg[fc][r] = p;
                rs += p;
            }
            #pragma unroll
            for (int off = 1; off < 16; off <<= 1)
                rs += __shfl_xor(rs, off, 16);
            lrow[r] = lrow[r] * corr + rs;
            mrow[r] = mn;
            #pragma unroll
            for (int hf = 0; hf < 4; ++hf)
                O[hf][r] *= corr;
        }

        // ---- P -> LDS packed (same-wave region) ----
        #pragma unroll
        for (int fc = 0; fc < 4; ++fc){
            #pragma unroll
            for (int r = 0; r < 4; ++r){
                Pt[w][(g*4 + r)*68 + fc*16 + c] = pack_split(pvreg[fc][r]);
            }
        }

        // ---- O += P @ V ----
        #pragma unroll
        for (int ks = 0; ks < 2; ++ks){
            const unsigned int* pp = &Pt[w][c*68 + ks*32 + g*8];
            uint4v pu0 = *(const uint4v*)pp;
            uint4v pu1 = *(const uint4v*)(pp + 4);
            short8 pah, pal;
            unpack8(pu0, pu1, pah, pal);
            #pragma unroll
            for (int hf = 0; hf < 4; ++hf){
                short8 vbh, vbl;
                rdfrag(Vt, hf*16 + c, ks*128 + g*32, vbh, vbl);
                __builtin_amdgcn_s_setprio(1);
                O[hf] = MFMA16(pah, vbh, O[hf]);
                O[hf] = MFMA16(pah, vbl, O[hf]);
                O[hf] = MFMA16(pal, vbh, O[hf]);
                __builtin_amdgcn_s_setprio(0);
            }
        }
        __syncthreads();
    }

    // ---- epilogue ----
    #pragma unroll
    for (int r = 0; r < 4; ++r){
        float inv = 1.0f / lrow[r];
        int rr = q0 + w*16 + g*4 + r;
        #pragma unroll
        for (int hf = 0; hf < 4; ++hf){
            int col = h*64 + hf*16 + c;
            o[((size_t)b * 512 + rr) * 768 + col] = pack_split(O[hf][r] * inv);
        }
    }
}

extern "C" void kernel_launch(void* const* d_in, const int* in_sizes, int n_in,
                              void* d_out, int out_size, void* d_ws, size_t ws_size,
                              hipStream_t stream)
{
    const float* x     = (const float*)d_in[0];
    const int*   adj   = (const int*)d_in[1];
    const int*   bond  = (const int*)d_in[2];
    const float* qkv_w = (const float*)d_in[4];
    const float* qkv_b = (const float*)d_in[5];
    const float* out_w = (const float*)d_in[6];
    const float* out_b = (const float*)d_in[7];
    const float* btab  = (const float*)d_in[8];
    float* out = (float*)d_out;

    const int QKV_ELEMS = 32 * 12 * 512 * 64;
    unsigned int* q  = (unsigned int*)d_ws;
    unsigned int* k  = q + QKV_ELEMS;
    unsigned int* vt = k + QKV_ELEMS;
    unsigned int* o  = vt + QKV_ELEMS;
    unsigned short* woh = (unsigned short*)(o + QKV_ELEMS);
    unsigned short* wol = woh + 768 * 768;
    unsigned short* wqh = wol + 768 * 768;
    unsigned short* wql = wqh + 2304 * 768;
    // biasC overlaps the qkv weight planes (dead after gemm1)
    float* biasC = (float*)(wqh);

    dim3 blk(256);
    split_kernel<<<dim3((2304*768 + 255)/256), blk, 0, stream>>>(qkv_w, wqh, wql, 2304*768);
    split_kernel<<<dim3((768*768 + 255)/256),  blk, 0, stream>>>(out_w, woh, wol, 768*768);

    // QKV projection: 2304 blocks = 8 XCDs x 16 row-tiles x 18 col-tiles
    gemm_split<0,1><<<dim3(2304), blk, 81920, stream>>>(
        x, wqh, wql, qkv_b, 2304, 768, 18, 16, nullptr, q, k, vt);

    // combined bias (after gemm1: overlaps wq planes)
    bias_kernel<<<dim3(8192), blk, 0, stream>>>(adj, bond, btab, biasC, (32*512*512)/4);

    // fused attention: 3072 blocks = 8 XCDs x 4 batches x 12 heads x 8 q-tiles
    attn_kernel<<<dim3(3072), blk, 0, stream>>>(q, k, vt, biasC, o);

    // output projection: 768 blocks = 8 XCDs x 16 row-tiles x 6 col-tiles
    gemm_split<1,0><<<dim3(768), blk, 81920, stream>>>(
        o, woh, wol, out_b, 768, 768, 6, 16, out, nullptr, nullptr, nullptr);
}

// Round 4
// 437.136 us; speedup vs baseline: 1.6728x; 1.0934x over previous
//
#include <hip/hip_runtime.h>
#include <hip/hip_bf16.h>

typedef __attribute__((ext_vector_type(8))) short short8;
typedef __attribute__((ext_vector_type(4))) float f32x4;
typedef __attribute__((ext_vector_type(4))) unsigned int uint4v;
typedef __attribute__((ext_vector_type(4))) int int4v;

#define MFMA16(a,b,c) __builtin_amdgcn_mfma_f32_16x16x32_bf16((a),(b),(c),0,0,0)

#define GLOAD_LDS16(g, l) \
    __builtin_amdgcn_global_load_lds((const __attribute__((address_space(1))) void*)(g), \
                                     (__attribute__((address_space(3))) void*)(l), 16, 0, 0)

// RNE fp32->bf16 (one-time weight packing)
__device__ __forceinline__ unsigned short f2bf(float f){
    union { float f; unsigned int u; } c; c.f = f;
    unsigned int u = c.u;
    u = (u + 0x7fffu + ((u >> 16) & 1u)) >> 16;
    return (unsigned short)u;
}
__device__ __forceinline__ float bf2f(unsigned short s){
    union { unsigned int u; float f; } c; c.u = ((unsigned int)s) << 16;
    return c.f;
}

// truncation split, packed (hi | lo<<16): 3 VALU
__device__ __forceinline__ unsigned int pack_split(float f){
    unsigned int u = __builtin_bit_cast(unsigned int, f);
    float hi = __builtin_bit_cast(float, u & 0xffff0000u);
    unsigned int rem = __builtin_bit_cast(unsigned int, f - hi);
    return __builtin_amdgcn_perm(rem, u, 0x07060302u);
}

// unpack 8 packed uints -> hi/lo bf16 short8 fragments: 8 v_perm
__device__ __forceinline__ void unpack8(uint4v u0, uint4v u1, short8& hi, short8& lo){
    uint4v h, l;
    h[0] = __builtin_amdgcn_perm(u0[1], u0[0], 0x05040100u);
    h[1] = __builtin_amdgcn_perm(u0[3], u0[2], 0x05040100u);
    h[2] = __builtin_amdgcn_perm(u1[1], u1[0], 0x05040100u);
    h[3] = __builtin_amdgcn_perm(u1[3], u1[2], 0x05040100u);
    l[0] = __builtin_amdgcn_perm(u0[1], u0[0], 0x07060302u);
    l[1] = __builtin_amdgcn_perm(u0[3], u0[2], 0x07060302u);
    l[2] = __builtin_amdgcn_perm(u1[1], u1[0], 0x07060302u);
    l[3] = __builtin_amdgcn_perm(u1[3], u1[2], 0x07060302u);
    hi = __builtin_bit_cast(short8, h);
    lo = __builtin_bit_cast(short8, l);
}

// ---------------- pack x into tile-images (truncation split, pre-swizzled) ----------------
// image block (mt, kt): 16 KB = [128 rows][32 uints], byte = row*128 + ((u*4) ^ ((row&7)<<4))
__global__ void pack_x_kernel(const float* __restrict__ x, unsigned int* __restrict__ img){
    int tid = blockIdx.x * 256 + threadIdx.x;        // 16384*192 threads
    int m = tid / 192, k4 = (tid - m*192) * 4;
    f32x4 v = *(const f32x4*)(x + (size_t)m*768 + k4);
    uint4v p;
    #pragma unroll
    for (int j = 0; j < 4; ++j) p[j] = pack_split(v[j]);
    int mt = m >> 7, row = m & 127, kt = k4 >> 5, u = k4 & 31;
    size_t off = ((size_t)(mt*24 + kt))*16384 + row*128 + (size_t)((u*4) ^ ((row&7)<<4));
    *(uint4v*)((char*)img + off) = p;
}

// ---------------- pack weights into tile-images (RNE split, pre-swizzled) ----------------
__global__ void pack_w_kernel(const float* __restrict__ wsrc, unsigned int* __restrict__ img, int total){
    int tid = blockIdx.x * 256 + threadIdx.x;
    if (tid >= total) return;
    int n = tid / 192, k4 = (tid - n*192) * 4;
    f32x4 v = *(const f32x4*)(wsrc + (size_t)n*768 + k4);
    uint4v p;
    #pragma unroll
    for (int j = 0; j < 4; ++j){
        unsigned short hh = f2bf(v[j]);
        unsigned short ll = f2bf(v[j] - bf2f(hh));
        p[j] = (unsigned int)hh | ((unsigned int)ll << 16);
    }
    int jt = n >> 7, row = n & 127, kt = k4 >> 5, u = k4 & 31;
    size_t off = ((size_t)(jt*24 + kt))*16384 + row*128 + (size_t)((u*4) ^ ((row&7)<<4));
    *(uint4v*)((char*)img + off) = p;
}

// ---------------- combined bias precompute: biasC = adj + table[bond] ----------------
__global__ void bias_kernel(const int* __restrict__ adj, const int* __restrict__ bond,
                            const float* __restrict__ table, float* __restrict__ biasC, int n4){
    int i = blockIdx.x * 256 + threadIdx.x;
    if (i >= n4) return;
    int4v a  = ((const int4v*)adj)[i];
    int4v bd = ((const int4v*)bond)[i];
    const float t1 = table[1], t2 = table[2], t3 = table[3], t4 = table[4];
    f32x4 o;
    #pragma unroll
    for (int j = 0; j < 4; ++j){
        int bv = bd[j];
        float tb = (bv == 1) ? t1 : (bv == 2) ? t2 : (bv == 3) ? t3 : (bv == 4) ? t4 : 0.0f;
        o[j] = (float)a[j] + tb;
    }
    ((f32x4*)biasC)[i] = o;
}

// ---------------- split-bf16 GEMM from tile-images (m97 structure) ----------------
// 128x128 tile, BK=32, 4 waves, single 32KB LDS buffer, global_load_lds staging.
// A/B images: per (tile, kt) 16 KB pre-swizzled packed-uint blocks.
template<int EMODE>
__global__ __launch_bounds__(256, 3)
void gemm_img(const unsigned int* __restrict__ Aimg, const unsigned int* __restrict__ Bimg,
              const float* __restrict__ bias, int NT, int RPX,
              float* __restrict__ C, int N,
              unsigned int* __restrict__ qo, unsigned int* __restrict__ ko,
              unsigned int* __restrict__ vo)
{
    __shared__ unsigned int lds[8192];   // A: [0..4095], B: [4096..8191]

    const int lin = blockIdx.x;
    const int xcd = lin & 7, idx = lin >> 3;
    // col-tiles grouped in 6s: W-panel (6 cols = 2.3 MB) stays L2-resident per group
    const int grp  = idx / (RPX * 6);
    const int rem  = idx - grp * (RPX * 6);
    const int rowL = rem / 6, c6 = rem - rowL * 6;
    const int colT = grp * 6 + c6;
    const int mt = xcd * RPX + rowL;
    const int m0 = mt << 7, j0 = colT << 7;

    const int t = threadIdx.x, l = t & 63, w = t >> 6;
    const int c = l & 15, g = l >> 4;
    const int wr = (w >> 1) * 64, wc2 = (w & 1) * 64;

    const unsigned int* Ablk = Aimg + (size_t)mt   * NT * 4096;
    const unsigned int* Bblk = Bimg + (size_t)colT * NT * 4096;

    f32x4 acc[4][4] = {};

    for (int kt = 0; kt < NT; ++kt){
        // ---- stage: pure DMA, linear LDS (images are pre-swizzled) ----
        const unsigned int* As = Ablk + kt*4096 + t*4;
        const unsigned int* Bs = Bblk + kt*4096 + t*4;
        unsigned int* Ad = lds + t*4;
        unsigned int* Bd = lds + 4096 + t*4;
        #pragma unroll
        for (int i = 0; i < 4; ++i){
            GLOAD_LDS16(As + i*1024, Ad + i*1024);
            GLOAD_LDS16(Bs + i*1024, Bd + i*1024);
        }
        __syncthreads();   // compiler emits vmcnt(0) drain here

        // ---- B fragment pairs (hoisted) ----
        short8 bh[4], bl[4];
        #pragma unroll
        for (int fc = 0; fc < 4; ++fc){
            int row = wc2 + fc*16 + c;
            int sw = (row & 7) << 4;
            const char* p = (const char*)(lds + 4096) + row*128;
            uint4v u0 = *(const uint4v*)(p + ((g*32     ) ^ sw));
            uint4v u1 = *(const uint4v*)(p + ((g*32 + 16) ^ sw));
            unpack8(u0, u1, bh[fc], bl[fc]);
        }
        // ---- A fragments on the fly + MFMA ----
        #pragma unroll
        for (int fr = 0; fr < 4; ++fr){
            int row = wr + fr*16 + c;
            int sw = (row & 7) << 4;
            const char* p = (const char*)lds + row*128;
            uint4v u0 = *(const uint4v*)(p + ((g*32     ) ^ sw));
            uint4v u1 = *(const uint4v*)(p + ((g*32 + 16) ^ sw));
            short8 ah, al;
            unpack8(u0, u1, ah, al);
            #pragma unroll
            for (int fc = 0; fc < 4; ++fc){
                acc[fr][fc] = MFMA16(ah, bh[fc], acc[fr][fc]);
                acc[fr][fc] = MFMA16(ah, bl[fc], acc[fr][fc]);
                acc[fr][fc] = MFMA16(al, bh[fc], acc[fr][fc]);
            }
        }
        __syncthreads();   // all reads done before next stage overwrites
    }

    // ---- epilogue ----
    #pragma unroll
    for (int fr = 0; fr < 4; ++fr){
        #pragma unroll
        for (int fc = 0; fc < 4; ++fc){
            #pragma unroll
            for (int r = 0; r < 4; ++r){
                int m = m0 + wr + fr*16 + g*4 + r;
                int j = j0 + wc2 + fc*16 + c;
                float val = acc[fr][fc][r] + bias[j];
                if constexpr (EMODE == 0){
                    C[(size_t)m * N + j] = val;
                } else {
                    int sec = j / 768;
                    int off = j - sec * 768;
                    int head = off >> 6, d = off & 63;
                    int bb = m >> 9, n = m & 511;
                    unsigned int packed = pack_split(val);
                    if (sec == 2) {
                        vo[(((size_t)bb * 12 + head) * 64 + d) * 512 + n] = packed;  // V transposed
                    } else {
                        unsigned int* dst = (sec == 0) ? qo : ko;
                        dst[(((size_t)bb * 12 + head) * 512 + n) * 64 + d] = packed;
                    }
                }
            }
        }
    }
}

// ---------------- fused flash attention (split-bf16 MFMA, packed LDS) ----------------
// 1D grid 3072, XCD-chunked. Output written directly as gemm2 A-images.
__global__ __launch_bounds__(256, 3)
void attn_kernel(const unsigned int* __restrict__ qb,
                 const unsigned int* __restrict__ kb,
                 const unsigned int* __restrict__ vtb,
                 const float* __restrict__ biasC,
                 unsigned int* __restrict__ oimg)
{
    __shared__ unsigned int Kt[64 * 64];
    __shared__ unsigned int Vt[64 * 64];
    __shared__ unsigned int Pt[4][16 * 68];

    const int lin = blockIdx.x;
    const int xcd = lin & 7, m_ = lin >> 3;
    const int bgrp = m_ / 96, r_ = m_ - bgrp * 96;
    const int b = (bgrp << 3) | xcd;
    const int h = r_ >> 3, qt = r_ & 7;
    const int bh = b * 12 + h, q0 = qt * 64;

    const int t = threadIdx.x, l = t & 63, w = t >> 6;
    const int c = l & 15, g = l >> 4;

    const unsigned int* qp  = qb  + (size_t)bh * 512 * 64;
    const unsigned int* kp  = kb  + (size_t)bh * 512 * 64;
    const unsigned int* vtp = vtb + (size_t)bh * 64 * 512;

    short8 qh[2], ql[2];
    {
        int qrow = q0 + w*16 + c;
        #pragma unroll
        for (int ks = 0; ks < 2; ++ks){
            const unsigned int* p = qp + (size_t)qrow * 64 + ks*32 + g*8;
            uint4v u0 = *(const uint4v*)p;
            uint4v u1 = *(const uint4v*)(p + 4);
            unpack8(u0, u1, qh[ks], ql[ks]);
        }
    }

    f32x4 O[4] = {};
    float mrow[4] = {-3e38f, -3e38f, -3e38f, -3e38f};
    float lrow[4] = {0.f, 0.f, 0.f, 0.f};

    const int srow = t >> 2;
    const int scol = (t & 3) * 16;
    const int ssw  = (srow & 7) << 4;

    auto rdfrag = [&](const unsigned int* base, int row, int colb, short8& hi, short8& lo){
        int sw = (row & 7) << 4;
        const char* p = (const char*)base + row*256;
        uint4v u0 = *(const uint4v*)(p + ((colb     ) ^ sw));
        uint4v u1 = *(const uint4v*)(p + ((colb + 16) ^ sw));
        unpack8(u0, u1, hi, lo);
    };

    for (int kt = 0; kt < 8; ++kt){
        {
            const unsigned int* kg = kp  + (size_t)(kt*64 + srow) * 64 + scol;
            const unsigned int* vg = vtp + (size_t)srow * 512 + kt*64 + scol;
            #pragma unroll
            for (int i = 0; i < 4; ++i){
                uint4v a  = *(const uint4v*)(kg + 4*i);
                uint4v bx = *(const uint4v*)(vg + 4*i);
                int cb = (scol + 4*i) * 4;
                *(uint4v*)((char*)Kt + srow*256 + (cb ^ ssw)) = a;
                *(uint4v*)((char*)Vt + srow*256 + (cb ^ ssw)) = bx;
            }
        }
        __syncthreads();

        float bia[4][4];
        #pragma unroll
        for (int fc = 0; fc < 4; ++fc){
            #pragma unroll
            for (int r = 0; r < 4; ++r){
                int rr = q0 + w*16 + g*4 + r;
                int cc = kt*64 + fc*16 + c;
                bia[fc][r] = biasC[((size_t)b * 512 + rr) * 512 + cc];
            }
        }

        f32x4 S[4] = {};
        #pragma unroll
        for (int fc = 0; fc < 4; ++fc){
            short8 kbh0, kbl0, kbh1, kbl1;
            rdfrag(Kt, fc*16 + c,       g*32, kbh0, kbl0);
            rdfrag(Kt, fc*16 + c, 128 + g*32, kbh1, kbl1);
            __builtin_amdgcn_s_setprio(1);
            S[fc] = MFMA16(qh[0], kbh0, S[fc]);
            S[fc] = MFMA16(qh[0], kbl0, S[fc]);
            S[fc] = MFMA16(ql[0], kbh0, S[fc]);
            S[fc] = MFMA16(qh[1], kbh1, S[fc]);
            S[fc] = MFMA16(qh[1], kbl1, S[fc]);
            S[fc] = MFMA16(ql[1], kbh1, S[fc]);
            __builtin_amdgcn_s_setprio(0);
        }

        float sv[4][4];
        #pragma unroll
        for (int fc = 0; fc < 4; ++fc){
            #pragma unroll
            for (int r = 0; r < 4; ++r){
                float val = fmaf(S[fc][r], 0.125f, bia[fc][r]);
                if (val == 0.0f) val = -1e9f;
                sv[fc][r] = val;
            }
        }

        float pvreg[4][4];
        #pragma unroll
        for (int r = 0; r < 4; ++r){
            float mt = fmaxf(fmaxf(sv[0][r], sv[1][r]), fmaxf(sv[2][r], sv[3][r]));
            #pragma unroll
            for (int off = 1; off < 16; off <<= 1)
                mt = fmaxf(mt, __shfl_xor(mt, off, 16));
            float mn = fmaxf(mrow[r], mt);
            float corr = __expf(mrow[r] - mn);
            float rs = 0.0f;
            #pragma unroll
            for (int fc = 0; fc < 4; ++fc){
                float p = __expf(sv[fc][r] - mn);
                pvreg[fc][r] = p;
                rs += p;
            }
            #pragma unroll
            for (int off = 1; off < 16; off <<= 1)
                rs += __shfl_xor(rs, off, 16);
            lrow[r] = lrow[r] * corr + rs;
            mrow[r] = mn;
            #pragma unroll
            for (int hf = 0; hf < 4; ++hf)
                O[hf][r] *= corr;
        }

        #pragma unroll
        for (int fc = 0; fc < 4; ++fc){
            #pragma unroll
            for (int r = 0; r < 4; ++r){
                Pt[w][(g*4 + r)*68 + fc*16 + c] = pack_split(pvreg[fc][r]);
            }
        }

        #pragma unroll
        for (int ks = 0; ks < 2; ++ks){
            const unsigned int* pp = &Pt[w][c*68 + ks*32 + g*8];
            uint4v pu0 = *(const uint4v*)pp;
            uint4v pu1 = *(const uint4v*)(pp + 4);
            short8 pah, pal;
            unpack8(pu0, pu1, pah, pal);
            #pragma unroll
            for (int hf = 0; hf < 4; ++hf){
                short8 vbh, vbl;
                rdfrag(Vt, hf*16 + c, ks*128 + g*32, vbh, vbl);
                __builtin_amdgcn_s_setprio(1);
                O[hf] = MFMA16(pah, vbh, O[hf]);
                O[hf] = MFMA16(pah, vbl, O[hf]);
                O[hf] = MFMA16(pal, vbh, O[hf]);
                __builtin_amdgcn_s_setprio(0);
            }
        }
        __syncthreads();
    }

    // ---- epilogue: write gemm2 A-images directly ----
    #pragma unroll
    for (int r = 0; r < 4; ++r){
        float inv = 1.0f / lrow[r];
        int m = b*512 + q0 + w*16 + g*4 + r;
        int mt = m >> 7, mrow2 = m & 127;
        int swz = (mrow2 & 7) << 4;
        size_t rowbase = ((size_t)mt*24)*16384 + (size_t)mrow2*128;
        #pragma unroll
        for (int hf = 0; hf < 4; ++hf){
            int e = h*64 + hf*16 + c;
            int kt2 = e >> 5, u = e & 31;
            size_t off = rowbase + (size_t)kt2*16384 + (size_t)((u*4) ^ swz);
            *(unsigned int*)((char*)oimg + off) = pack_split(O[hf][r] * inv);
        }
    }
}

extern "C" void kernel_launch(void* const* d_in, const int* in_sizes, int n_in,
                              void* d_out, int out_size, void* d_ws, size_t ws_size,
                              hipStream_t stream)
{
    const float* x     = (const float*)d_in[0];
    const int*   adj   = (const int*)d_in[1];
    const int*   bond  = (const int*)d_in[2];
    const float* qkv_w = (const float*)d_in[4];
    const float* qkv_b = (const float*)d_in[5];
    const float* out_w = (const float*)d_in[6];
    const float* out_b = (const float*)d_in[7];
    const float* btab  = (const float*)d_in[8];
    float* out = (float*)d_out;

    // ws layout (dwords). Total 237.2 MB == round-3 proven footprint.
    const size_t QKV = 12582912;                 // 32*12*512*64
    unsigned int* q   = (unsigned int*)d_ws;
    unsigned int* k   = q  + QKV;
    unsigned int* vt  = k  + QKV;
    unsigned int* r1  = vt + QKV;                // x-images (gemm1 A), then o-images (gemm2 A); 128*24*4096 == QKV dwords
    unsigned int* w2i = r1 + QKV;                // 6*24*4096 = 589824
    unsigned int* r2  = w2i + 589824;            // W1 images (1769472 dw) overlapped by biasC (8388608 f32), written after gemm1
    unsigned int* w1i = r2;
    float* biasC      = (float*)r2;

    dim3 blk(256);
    pack_w_kernel<<<dim3(1728), blk, 0, stream>>>(qkv_w, w1i, 2304*192);
    pack_w_kernel<<<dim3(576),  blk, 0, stream>>>(out_w, w2i, 768*192);
    pack_x_kernel<<<dim3(12288), blk, 0, stream>>>(x, r1);

    // QKV projection: 2304 blocks = 8 XCDs x (3 col-groups x 16 rows x 6 cols)
    gemm_img<1><<<dim3(2304), blk, 0, stream>>>(r1, w1i, qkv_b, 24, 16,
                                                nullptr, 2304, q, k, vt);

    // biasC overlaps W1 images -> strictly after gemm1 (stream order)
    bias_kernel<<<dim3(8192), blk, 0, stream>>>(adj, bond, btab, biasC, (32*512*512)/4);

    // fused attention: writes o-images into r1 (x-images dead after gemm1)
    attn_kernel<<<dim3(3072), blk, 0, stream>>>(q, k, vt, biasC, r1);

    // output projection: 768 blocks = 8 XCDs x (16 rows x 6 cols)
    gemm_img<0><<<dim3(768), blk, 0, stream>>>(r1, w2i, out_b, 24, 16,
                                               out, 768, nullptr, nullptr, nullptr);
}